// Round 7
// baseline (168.750 us; speedup 1.0000x reference)
//
#include <hip/hip_runtime.h>
#include <math.h>

typedef unsigned short u16;
typedef unsigned int u32;
typedef __attribute__((ext_vector_type(4))) float f32x4;
typedef __attribute__((ext_vector_type(8))) short s16x8;
typedef __attribute__((ext_vector_type(4))) unsigned short u16x4;

#define T_ 2048
#define C_ 1024

// fp32 -> bf16, round-half-up
__device__ __forceinline__ u16 f2b(float f) {
  u32 u = __builtin_bit_cast(u32, f);
  return (u16)((u + 0x8000u) >> 16);
}

__device__ __forceinline__ s16x8 pack8v(f32x4 a, f32x4 b) {
  s16x8 r;
  r[0] = (short)f2b(a[0]); r[1] = (short)f2b(a[1]);
  r[2] = (short)f2b(a[2]); r[3] = (short)f2b(a[3]);
  r[4] = (short)f2b(b[0]); r[5] = (short)f2b(b[1]);
  r[6] = (short)f2b(b[2]); r[7] = (short)f2b(b[3]);
  return r;
}

// async global->LDS, 16B per lane; LDS dest = wave-uniform base + lane*16
__device__ __forceinline__ void gld_lds16(const void* g, void* l) {
  __builtin_amdgcn_global_load_lds(
      (const __attribute__((address_space(1))) u32*)g,
      (__attribute__((address_space(3))) u32*)l, 16, 0, 0);
}

// ---------------- kernel 0: weights fp32 [1024][64] x3 -> Wt bf16 [192][1024]
// transposed (k-contiguous). Softmax scale 1/8 AND log2(e) folded into W_q.
__global__ __launch_bounds__(256) void wconv(const float* __restrict__ Wq,
                                             const float* __restrict__ Wk,
                                             const float* __restrict__ Wv,
                                             u16* __restrict__ Wt) {
  __shared__ u16 t[64][68];
  const int bm = blockIdx.x >> 4;   // matrix 0..2
  const int kt = blockIdx.x & 15;   // k-tile of 64
  const float* src = (bm == 0) ? Wq : ((bm == 1) ? Wk : Wv);
  const float scale = (bm == 0) ? 0.18033688f : 1.0f;  // 0.125 * log2(e)
  const int krow = threadIdx.x >> 2;
  const int c0 = (threadIdx.x & 3) * 16;
  const float* sp = src + (size_t)(kt * 64 + krow) * 64 + c0;
#pragma unroll
  for (int i = 0; i < 4; ++i) {
    float4 v = *(const float4*)(sp + i * 4);
    t[c0 + i * 4 + 0][krow] = f2b(v.x * scale);
    t[c0 + i * 4 + 1][krow] = f2b(v.y * scale);
    t[c0 + i * 4 + 2][krow] = f2b(v.z * scale);
    t[c0 + i * 4 + 3][krow] = f2b(v.w * scale);
  }
  __syncthreads();
  const int n = threadIdx.x >> 2;
  const int koff = (threadIdx.x & 3) * 16;
  u16* dst = Wt + (size_t)(bm * 64 + n) * C_ + kt * 64 + koff;
#pragma unroll
  for (int i = 0; i < 4; ++i)
    *(u16x4*)(dst + i * 4) = *(const u16x4*)(&t[n][koff + i * 4]);
}

// ---------------- kernel 1: qkv projection — BK=128 (8 barrier rounds).
// M=32, grid 512 (2 blocks/CU), 4 waves = 2 m-subtiles x 2 n-halves.
// Per round: stage x (32x128 fp32, 16 KB) + W (192x128 bf16, 48 KB) via
// global_load_lds w=16, XOR-swizzled on the GLOBAL side; 24 MFMA/wave.
// Fewer lockstep rounds with 2x in-flight depth vs R6 (the 40-us driver).
__global__ __launch_bounds__(256, 2) void proj(const float* __restrict__ x,
                                               const u16* __restrict__ Wt,
                                               u16* __restrict__ qo,
                                               u16* __restrict__ ko,
                                               u16* __restrict__ vt) {
  __shared__ __align__(16) u32 smem[16384];      // 64 KB
  float* xs = (float*)smem;                      // [32][128] fp32, 16 KB
  u16* wsh = (u16*)(smem + 4096);                // [192][128] bf16, 48 KB
  const int tid = threadIdx.x;
  const int wave = tid >> 6, lane = tid & 63;
  const int quad = lane >> 4, l15 = lane & 15;
  const int mg = wave >> 1, nh = wave & 1;
  const int m0 = blockIdx.x * 32;

  // x staging: per call 2 rows x 32 chunks(16B); slot s of row r holds
  // global chunk s ^ (r&31).
  const int xslot = lane & 31, xrin = lane >> 5;
  // W staging: per call 4 rows x 16 chunks; slot s of row r holds s ^ (r&15).
  const int wslot = lane & 15, wrin = lane >> 4;

  f32x4 acc[6];
#pragma unroll
  for (int j = 0; j < 6; ++j) acc[j] = {0.f, 0.f, 0.f, 0.f};

  for (int kt = 0; kt < 8; ++kt) {
    const int k0 = kt * 128;
    // ---- stage x: 4 calls/wave
#pragma unroll
    for (int c = 0; c < 4; ++c) {
      const int row = wave * 8 + c * 2 + xrin;
      const int g = xslot ^ (row & 31);
      gld_lds16(x + (size_t)(m0 + row) * C_ + k0 + g * 4,
                &xs[(wave * 8 + c * 2) * 128]);
    }
    // ---- stage W: 12 calls/wave
#pragma unroll
    for (int c = 0; c < 12; ++c) {
      const int row = (wave * 12 + c) * 4 + wrin;
      const int g = wslot ^ (row & 15);
      gld_lds16(Wt + (size_t)row * C_ + k0 + g * 8,
                &wsh[(wave * 12 + c) * 4 * 128]);
    }
    __syncthreads();
    // ---- A frags: row r = 16mg+l15; ks=0..3, float-chunks 2ks*?.. per frag
    const int r = 16 * mg + l15;
    s16x8 af[4];
#pragma unroll
    for (int ks = 0; ks < 4; ++ks) {
      const int cc = ks * 8 + quad * 2;
      f32x4 p0 = *(const f32x4*)&xs[r * 128 + ((cc ^ (r & 31)) * 4)];
      f32x4 p1 = *(const f32x4*)&xs[r * 128 + (((cc + 1) ^ (r & 31)) * 4)];
      af[ks] = pack8v(p0, p1);
    }
    // ---- B frags + MFMA
#pragma unroll
    for (int jj = 0; jj < 6; ++jj) {
      const int R = (nh * 6 + jj) * 16 + l15;
#pragma unroll
      for (int ks = 0; ks < 4; ++ks) {
        const int cc = ks * 4 + quad;
        s16x8 bf = *(const s16x8*)&wsh[R * 128 + ((cc ^ (R & 15)) * 8)];
        acc[jj] = __builtin_amdgcn_mfma_f32_16x16x32_bf16(af[ks], bf, acc[jj], 0, 0, 0);
      }
    }
    __syncthreads();
  }

  // epilogue: C[m=x-row][n=W-row]; col=l15 (n), row=quad*4+i (m)
  const int r0 = m0 + 16 * mg + quad * 4;
#pragma unroll
  for (int jj = 0; jj < 6; ++jj) {
    const int ns = nh * 6 + jj;
    if (ns < 4) {
      const int col = ns * 16 + l15;
#pragma unroll
      for (int i = 0; i < 4; ++i)
        qo[(size_t)(r0 + i) * 64 + col] = f2b(acc[jj][i]);
    } else if (ns < 8) {
      const int col = (ns - 4) * 16 + l15;
#pragma unroll
      for (int i = 0; i < 4; ++i)
        ko[(size_t)(r0 + i) * 64 + col] = f2b(acc[jj][i]);
    } else {
      const int d = (ns - 8) * 16 + l15;
      const int bb = r0 >> 11, t0 = r0 & 2047;
      u16x4 pk = {f2b(acc[jj][0]), f2b(acc[jj][1]), f2b(acc[jj][2]), f2b(acc[jj][3])};
      *(u16x4*)(vt + (size_t)bb * (64 * T_) + (size_t)d * T_ + t0) = pk;
    }
  }
}

// ---------------- kernel 2: causal flash attention — TLP + register-neutral
// K prefetch. q-tile 16; grid 1024 (4 blocks/CU, 16 waves/CU); b = blk&7
// (XCD-affine), qt heavy-first. 4 waves split kv-tiles (j = w, w+4, ...).
// K(j+4) is loaded into the SAME kf regs right after the S-MFMAs consume
// them (anti-dep pins issue point) -> remote-L2 K latency hidden behind
// softmax+PV. V(j) issues a full S+softmax ahead of its use.
__global__ __launch_bounds__(256, 4) void attn(const u16* __restrict__ qw,
                                               const u16* __restrict__ kw,
                                               const u16* __restrict__ vt,
                                               float* __restrict__ out) {
  __shared__ __align__(16) u16 Pb[4][16 * 72];  // per-wave P; reused for O
  __shared__ float mbuf[4][16];
  __shared__ float lbuf[4][16];
  const int tid = threadIdx.x;
  const int wave = tid >> 6, lane = tid & 63;
  const int quad = lane >> 4, l15 = lane & 15;
  const int b = blockIdx.x & 7;
  const int qt = 127 - (blockIdx.x >> 3);  // heavy q-tiles first

  const u16* qp = qw + ((size_t)b * T_ + qt * 16) * 64;
  const u16* kb = kw + (size_t)b * T_ * 64;
  const u16* vb = vt + (size_t)b * 64 * T_;

  s16x8 qf[2];  // Q as B-operand: q-row n = l15, k = ks*32+quad*8+i
#pragma unroll
  for (int ks = 0; ks < 2; ++ks)
    qf[ks] = *(const s16x8*)(qp + l15 * 64 + ks * 32 + quad * 8);

  f32x4 o[4];  // O^T acc: subtile m over d, col = q = l15
#pragma unroll
  for (int m = 0; m < 4; ++m) o[m] = {0.f, 0.f, 0.f, 0.f};
  float mr = -INFINITY, lr = 0.0f;

  u16* P = Pb[wave];
  const int jd = qt >> 2;  // last (diagonal-overlapping) 64-wide kv tile

  s16x8 kf[2][4];
  if (wave <= jd) {  // preload K of first tile
    const u16* kp = kb + (size_t)wave * 64 * 64;
#pragma unroll
    for (int ks = 0; ks < 2; ++ks)
#pragma unroll
      for (int m = 0; m < 4; ++m)
        kf[ks][m] = *(const s16x8*)(kp + (16 * m + l15) * 64 + ks * 32 + quad * 8);
  }

  for (int j = wave; j <= jd; j += 4) {
    const u16* vp = vb + j * 64;
    s16x8 vf[2][4];
#pragma unroll
    for (int ks = 0; ks < 2; ++ks)
#pragma unroll
      for (int m = 0; m < 4; ++m)
        vf[ks][m] = *(const s16x8*)(vp + (size_t)(16 * m + l15) * T_ + ks * 32 + quad * 8);

    f32x4 s[4];  // S^T: kv subtile m, q col = l15
#pragma unroll
    for (int m = 0; m < 4; ++m) s[m] = {0.f, 0.f, 0.f, 0.f};
#pragma unroll
    for (int ks = 0; ks < 2; ++ks)
#pragma unroll
      for (int m = 0; m < 4; ++m)
        s[m] = __builtin_amdgcn_mfma_f32_16x16x32_bf16(kf[ks][m], qf[ks], s[m], 0, 0, 0);

    // prefetch K(j+4) into the just-consumed kf regs (clamped, loop-carried)
    {
      const int jn = (j + 4 <= jd) ? j + 4 : jd;
      const u16* kp = kb + (size_t)jn * 64 * 64;
#pragma unroll
      for (int ks = 0; ks < 2; ++ks)
#pragma unroll
        for (int m = 0; m < 4; ++m)
          kf[ks][m] = *(const s16x8*)(kp + (16 * m + l15) * 64 + ks * 32 + quad * 8);
    }

    if (j == jd) {  // diagonal: kv_g = 64j+16m+quad*4+i vs q_g = 16qt+l15
#pragma unroll
      for (int m = 0; m < 4; ++m)
#pragma unroll
        for (int i = 0; i < 4; ++i)
          if (64 * jd + 16 * m + quad * 4 + i > 16 * qt + l15) s[m][i] = -INFINITY;
    }
    // online softmax over 16 in-lane values + cross-quad (xor16, xor32)
    float mt = s[0][0];
#pragma unroll
    for (int m = 0; m < 4; ++m)
#pragma unroll
      for (int i = 0; i < 4; ++i) mt = fmaxf(mt, s[m][i]);
    mt = fmaxf(mt, __shfl_xor(mt, 16));
    mt = fmaxf(mt, __shfl_xor(mt, 32));
    const float mn = fmaxf(mr, mt);
    const float al = exp2f(mr - mn);
    mr = mn;
    float rs = 0.0f;
#pragma unroll
    for (int m = 0; m < 4; ++m)
#pragma unroll
      for (int i = 0; i < 4; ++i) {
        float p = exp2f(s[m][i] - mn);
        s[m][i] = p;
        rs += p;
      }
    rs += __shfl_xor(rs, 16);
    rs += __shfl_xor(rs, 32);
    lr = lr * al + rs;
    // P -> LDS row-major [q=l15][kv] (stride 72), packed 8B (wave-private)
#pragma unroll
    for (int m = 0; m < 4; ++m) {
      u16x4 pk = {f2b(s[m][0]), f2b(s[m][1]), f2b(s[m][2]), f2b(s[m][3])};
      *(u16x4*)(&P[l15 * 72 + 16 * m + quad * 4]) = pk;
    }
#pragma unroll
    for (int m = 0; m < 4; ++m) o[m] *= al;
    // O^T += V^T (A, regs) . P^T (B: n=q=l15, k from P row)
#pragma unroll
    for (int ks = 0; ks < 2; ++ks) {
      s16x8 pf = *(const s16x8*)(&P[l15 * 72 + ks * 32 + quad * 8]);
#pragma unroll
      for (int m = 0; m < 4; ++m)
        o[m] = __builtin_amdgcn_mfma_f32_16x16x32_bf16(vf[ks][m], pf, o[m], 0, 0, 0);
    }
  }
  // stats (replicated across quads post-reduce) + O^T -> LDS [q=l15][d] bf16
  if (quad == 0) {
    mbuf[wave][l15] = mr;
    lbuf[wave][l15] = lr;
  }
#pragma unroll
  for (int m = 0; m < 4; ++m) {
    u16x4 pk = {f2b(o[m][0]), f2b(o[m][1]), f2b(o[m][2]), f2b(o[m][3])};
    *(u16x4*)(&Pb[wave][l15 * 72 + 16 * m + quad * 4]) = pk;
  }
  __syncthreads();
  // merge 4 wave-partials: thread -> q-row r (16), d-chunk cg (4 wide)
  const int r = tid >> 4;
  const int cg = (tid & 15) * 4;
  float fw[4];
  float mstar = -INFINITY, lsum = 0.0f;
#pragma unroll
  for (int w = 0; w < 4; ++w) mstar = fmaxf(mstar, mbuf[w][r]);
#pragma unroll
  for (int w = 0; w < 4; ++w) {
    fw[w] = exp2f(mbuf[w][r] - mstar);
    lsum += fw[w] * lbuf[w][r];
  }
  const float inv = 1.0f / lsum;
  float a0 = 0.f, a1 = 0.f, a2 = 0.f, a3 = 0.f;
#pragma unroll
  for (int w = 0; w < 4; ++w) {
    u16x4 vv = *(const u16x4*)(&Pb[w][r * 72 + cg]);
    a0 += fw[w] * __builtin_bit_cast(float, ((u32)vv[0]) << 16);
    a1 += fw[w] * __builtin_bit_cast(float, ((u32)vv[1]) << 16);
    a2 += fw[w] * __builtin_bit_cast(float, ((u32)vv[2]) << 16);
    a3 += fw[w] * __builtin_bit_cast(float, ((u32)vv[3]) << 16);
  }
  float4 st = {a0 * inv, a1 * inv, a2 * inv, a3 * inv};
  *(float4*)(out + ((size_t)b * T_ + qt * 16 + r) * 64 + cg) = st;
}

extern "C" void kernel_launch(void* const* d_in, const int* in_sizes, int n_in,
                              void* d_out, int out_size, void* d_ws, size_t ws_size,
                              hipStream_t stream) {
  const float* x  = (const float*)d_in[0];
  const float* Wq = (const float*)d_in[1];
  const float* Wk = (const float*)d_in[2];
  const float* Wv = (const float*)d_in[3];
  float* out = (float*)d_out;
  char* ws = (char*)d_ws;
  u16* Wt = (u16*)ws;                                   // 384 KB
  u16* q  = (u16*)(ws + 393216);                        // 2 MB
  u16* k  = (u16*)(ws + 393216 + 2097152);              // 2 MB
  u16* vT = (u16*)(ws + 393216 + 2 * 2097152);          // 2 MB
  hipLaunchKernelGGL(wconv, dim3(48), dim3(256), 0, stream, Wq, Wk, Wv, Wt);
  hipLaunchKernelGGL(proj, dim3(512), dim3(256), 0, stream, x, Wt, q, k, vT);
  hipLaunchKernelGGL(attn, dim3(1024), dim3(256), 0, stream, q, k, vT, out);
}

// Round 8
// 132.011 us; speedup vs baseline: 1.2783x; 1.2783x over previous
//
#include <hip/hip_runtime.h>
#include <math.h>

typedef unsigned short u16;
typedef unsigned int u32;
typedef __attribute__((ext_vector_type(4))) float f32x4;
typedef __attribute__((ext_vector_type(8))) short s16x8;
typedef __attribute__((ext_vector_type(4))) unsigned short u16x4;

#define T_ 2048
#define C_ 1024

// fp32 -> bf16, round-half-up
__device__ __forceinline__ u16 f2b(float f) {
  u32 u = __builtin_bit_cast(u32, f);
  return (u16)((u + 0x8000u) >> 16);
}

__device__ __forceinline__ s16x8 pack8v(f32x4 a, f32x4 b) {
  s16x8 r;
  r[0] = (short)f2b(a[0]); r[1] = (short)f2b(a[1]);
  r[2] = (short)f2b(a[2]); r[3] = (short)f2b(a[3]);
  r[4] = (short)f2b(b[0]); r[5] = (short)f2b(b[1]);
  r[6] = (short)f2b(b[2]); r[7] = (short)f2b(b[3]);
  return r;
}

// async global->LDS, 16B per lane; LDS dest = wave-uniform base + lane*16
__device__ __forceinline__ void gld_lds16(const void* g, void* l) {
  __builtin_amdgcn_global_load_lds(
      (const __attribute__((address_space(1))) u32*)g,
      (__attribute__((address_space(3))) u32*)l, 16, 0, 0);
}

// ---------------- kernel 0: weights fp32 [1024][64] x3 -> Wt bf16 [192][1024]
// transposed (k-contiguous). Softmax scale 1/8 AND log2(e) folded into W_q.
__global__ __launch_bounds__(256) void wconv(const float* __restrict__ Wq,
                                             const float* __restrict__ Wk,
                                             const float* __restrict__ Wv,
                                             u16* __restrict__ Wt) {
  __shared__ u16 t[64][68];
  const int bm = blockIdx.x >> 4;   // matrix 0..2
  const int kt = blockIdx.x & 15;   // k-tile of 64
  const float* src = (bm == 0) ? Wq : ((bm == 1) ? Wk : Wv);
  const float scale = (bm == 0) ? 0.18033688f : 1.0f;  // 0.125 * log2(e)
  const int krow = threadIdx.x >> 2;
  const int c0 = (threadIdx.x & 3) * 16;
  const float* sp = src + (size_t)(kt * 64 + krow) * 64 + c0;
#pragma unroll
  for (int i = 0; i < 4; ++i) {
    float4 v = *(const float4*)(sp + i * 4);
    t[c0 + i * 4 + 0][krow] = f2b(v.x * scale);
    t[c0 + i * 4 + 1][krow] = f2b(v.y * scale);
    t[c0 + i * 4 + 2][krow] = f2b(v.z * scale);
    t[c0 + i * 4 + 3][krow] = f2b(v.w * scale);
  }
  __syncthreads();
  const int n = threadIdx.x >> 2;
  const int koff = (threadIdx.x & 3) * 16;
  u16* dst = Wt + (size_t)(bm * 64 + n) * C_ + kt * 64 + koff;
#pragma unroll
  for (int i = 0; i < 4; ++i)
    *(u16x4*)(dst + i * 4) = *(const u16x4*)(&t[n][koff + i * 4]);
}

// ---------------- kernel 1: qkv projection — BK=128, unchanged from R7.
__global__ __launch_bounds__(256, 2) void proj(const float* __restrict__ x,
                                               const u16* __restrict__ Wt,
                                               u16* __restrict__ qo,
                                               u16* __restrict__ ko,
                                               u16* __restrict__ vt) {
  __shared__ __align__(16) u32 smem[16384];      // 64 KB
  float* xs = (float*)smem;                      // [32][128] fp32, 16 KB
  u16* wsh = (u16*)(smem + 4096);                // [192][128] bf16, 48 KB
  const int tid = threadIdx.x;
  const int wave = tid >> 6, lane = tid & 63;
  const int quad = lane >> 4, l15 = lane & 15;
  const int mg = wave >> 1, nh = wave & 1;
  const int m0 = blockIdx.x * 32;

  const int xslot = lane & 31, xrin = lane >> 5;
  const int wslot = lane & 15, wrin = lane >> 4;

  f32x4 acc[6];
#pragma unroll
  for (int j = 0; j < 6; ++j) acc[j] = {0.f, 0.f, 0.f, 0.f};

  for (int kt = 0; kt < 8; ++kt) {
    const int k0 = kt * 128;
#pragma unroll
    for (int c = 0; c < 4; ++c) {
      const int row = wave * 8 + c * 2 + xrin;
      const int g = xslot ^ (row & 31);
      gld_lds16(x + (size_t)(m0 + row) * C_ + k0 + g * 4,
                &xs[(wave * 8 + c * 2) * 128]);
    }
#pragma unroll
    for (int c = 0; c < 12; ++c) {
      const int row = (wave * 12 + c) * 4 + wrin;
      const int g = wslot ^ (row & 15);
      gld_lds16(Wt + (size_t)row * C_ + k0 + g * 8,
                &wsh[(wave * 12 + c) * 4 * 128]);
    }
    __syncthreads();
    const int r = 16 * mg + l15;
    s16x8 af[4];
#pragma unroll
    for (int ks = 0; ks < 4; ++ks) {
      const int cc = ks * 8 + quad * 2;
      f32x4 p0 = *(const f32x4*)&xs[r * 128 + ((cc ^ (r & 31)) * 4)];
      f32x4 p1 = *(const f32x4*)&xs[r * 128 + (((cc + 1) ^ (r & 31)) * 4)];
      af[ks] = pack8v(p0, p1);
    }
#pragma unroll
    for (int jj = 0; jj < 6; ++jj) {
      const int R = (nh * 6 + jj) * 16 + l15;
#pragma unroll
      for (int ks = 0; ks < 4; ++ks) {
        const int cc = ks * 4 + quad;
        s16x8 bf = *(const s16x8*)&wsh[R * 128 + ((cc ^ (R & 15)) * 8)];
        acc[jj] = __builtin_amdgcn_mfma_f32_16x16x32_bf16(af[ks], bf, acc[jj], 0, 0, 0);
      }
    }
    __syncthreads();
  }

  const int r0 = m0 + 16 * mg + quad * 4;
#pragma unroll
  for (int jj = 0; jj < 6; ++jj) {
    const int ns = nh * 6 + jj;
    if (ns < 4) {
      const int col = ns * 16 + l15;
#pragma unroll
      for (int i = 0; i < 4; ++i)
        qo[(size_t)(r0 + i) * 64 + col] = f2b(acc[jj][i]);
    } else if (ns < 8) {
      const int col = (ns - 4) * 16 + l15;
#pragma unroll
      for (int i = 0; i < 4; ++i)
        ko[(size_t)(r0 + i) * 64 + col] = f2b(acc[jj][i]);
    } else {
      const int d = (ns - 8) * 16 + l15;
      const int bb = r0 >> 11, t0 = r0 & 2047;
      u16x4 pk = {f2b(acc[jj][0]), f2b(acc[jj][1]), f2b(acc[jj][2]), f2b(acc[jj][3])};
      *(u16x4*)(vt + (size_t)bb * (64 * T_) + (size_t)d * T_ + t0) = pk;
    }
  }
}

// ---------------- kernel 2: causal flash attention — COALESCED LDS-staged
// K/V (the R7 lesson: scattered frag loads saturate L1 request throughput;
// stage contiguously with global_load_lds, scatter only inside LDS).
// Bq=32; grid 512 (2 blocks/CU), b=blk&7 (XCD-affine), qt heavy-first.
// 4 waves = 2 q-groups (16 rows) x 2 kv-parity groups. Per round: stage two
// 64-wide K + V^T tiles (32 KB, XOR-swizzled global side) double-buffered;
// stage r+1 issues BEFORE compute r. 2-way end merge per q-row.
__global__ __launch_bounds__(256, 2) void attn(const u16* __restrict__ qw,
                                               const u16* __restrict__ kw,
                                               const u16* __restrict__ vt,
                                               float* __restrict__ out) {
  __shared__ __align__(16) u16 kvb[2][2][2][4096];  // [buf][tile][K/V][64x64]
  __shared__ __align__(16) u16 Ob[4][16 * 72];      // per-wave P; reused for O
  __shared__ float mbuf[4][16];
  __shared__ float lbuf[4][16];
  const int tid = threadIdx.x;
  const int wave = tid >> 6, lane = tid & 63;
  const int quad = lane >> 4, l15 = lane & 15;
  const int qg = wave >> 1, kg = wave & 1;
  const int b = blockIdx.x & 7;
  const int qt = 63 - (blockIdx.x >> 3);  // heavy q-tiles first

  const u16* qp = qw + ((size_t)b * T_ + qt * 32 + 16 * qg) * 64;
  const u16* kb = kw + (size_t)b * T_ * 64;
  const u16* vb = vt + (size_t)b * 64 * T_;

  const int jd = qt >> 1;           // last 64-wide kv tile
  const int R = (jd + 2) >> 1;      // rounds = ceil((jd+1)/2)

  s16x8 qf[2];  // Q as B-operand: q-row n = l15, k = ks*32+quad*8+i
#pragma unroll
  for (int ks = 0; ks < 2; ++ks)
    qf[ks] = *(const s16x8*)(qp + l15 * 64 + ks * 32 + quad * 8);

  f32x4 o[4];  // O^T acc: subtile m over d, col = q = l15
#pragma unroll
  for (int m = 0; m < 4; ++m) o[m] = {0.f, 0.f, 0.f, 0.f};
  float mr = -INFINITY, lr = 0.0f;

  u16* P = Ob[wave];

  // staging lane roles: 8 rows x 8 chunks(16B) per 1 KB call
  const int rin = lane >> 3, slot = lane & 7;
  const int g8 = slot ^ rin;  // global chunk index (XOR swizzle key = row&7)

  // wave role in staging: tile (wave>>1) of this round, K (wave&1==0) or V
  auto stage = [&](int r) {
    const int j = 2 * r + (wave >> 1);
    if (j > jd) return;
    u16* dst = kvb[r & 1][wave >> 1][wave & 1];
    if ((wave & 1) == 0) {  // K tile: rows 64j.., 128B/row
#pragma unroll
      for (int c = 0; c < 8; ++c)
        gld_lds16(kb + (size_t)(64 * j + 8 * c + rin) * 64 + g8 * 8,
                  dst + c * 512);
    } else {  // V^T tile: rows d=0..63, row d at vb + d*T_ + 64j
#pragma unroll
      for (int c = 0; c < 8; ++c)
        gld_lds16(vb + (size_t)(8 * c + rin) * T_ + 64 * j + g8 * 8,
                  dst + c * 512);
    }
  };

  stage(0);
  __syncthreads();

  for (int r = 0; r < R; ++r) {
    if (r + 1 < R) stage(r + 1);  // lands in other buffer; overlaps compute
    const int j = 2 * r + kg;
    if (j <= jd) {
      const u16* Kt = kvb[r & 1][kg][0];
      const u16* Vt = kvb[r & 1][kg][1];
      f32x4 s[4];
#pragma unroll
      for (int m = 0; m < 4; ++m) s[m] = {0.f, 0.f, 0.f, 0.f};
#pragma unroll
      for (int ks = 0; ks < 2; ++ks)
#pragma unroll
        for (int m = 0; m < 4; ++m) {
          const int row = 16 * m + l15;
          const int sl = (ks * 4 + quad) ^ (row & 7);
          s16x8 kf = *(const s16x8*)&Kt[row * 64 + sl * 8];
          s[m] = __builtin_amdgcn_mfma_f32_16x16x32_bf16(kf, qf[ks], s[m], 0, 0, 0);
        }
      if (j == jd) {  // diagonal: kv_g = 64j+16m+quad*4+i vs q_g
#pragma unroll
        for (int m = 0; m < 4; ++m)
#pragma unroll
          for (int i = 0; i < 4; ++i)
            if (64 * jd + 16 * m + quad * 4 + i > 32 * qt + 16 * qg + l15)
              s[m][i] = -INFINITY;
      }
      float mt = s[0][0];
#pragma unroll
      for (int m = 0; m < 4; ++m)
#pragma unroll
        for (int i = 0; i < 4; ++i) mt = fmaxf(mt, s[m][i]);
      mt = fmaxf(mt, __shfl_xor(mt, 16));
      mt = fmaxf(mt, __shfl_xor(mt, 32));
      const float mn = fmaxf(mr, mt);
      const float al = exp2f(mr - mn);
      mr = mn;
      float rs = 0.0f;
#pragma unroll
      for (int m = 0; m < 4; ++m)
#pragma unroll
        for (int i = 0; i < 4; ++i) {
          float p = exp2f(s[m][i] - mn);
          s[m][i] = p;
          rs += p;
        }
      rs += __shfl_xor(rs, 16);
      rs += __shfl_xor(rs, 32);
      lr = lr * al + rs;
      // P -> LDS [q=l15][kv] (stride 72), packed 8B (wave-private)
#pragma unroll
      for (int m = 0; m < 4; ++m) {
        u16x4 pk = {f2b(s[m][0]), f2b(s[m][1]), f2b(s[m][2]), f2b(s[m][3])};
        *(u16x4*)(&P[l15 * 72 + 16 * m + quad * 4]) = pk;
      }
#pragma unroll
      for (int m = 0; m < 4; ++m) o[m] *= al;
      // O^T += V^T (A, from LDS) . P^T (B)
#pragma unroll
      for (int ks = 0; ks < 2; ++ks) {
        s16x8 pf = *(const s16x8*)(&P[l15 * 72 + ks * 32 + quad * 8]);
#pragma unroll
        for (int m = 0; m < 4; ++m) {
          const int row = 16 * m + l15;
          const int sl = (ks * 4 + quad) ^ (row & 7);
          s16x8 vf = *(const s16x8*)&Vt[row * 64 + sl * 8];
          o[m] = __builtin_amdgcn_mfma_f32_16x16x32_bf16(vf, pf, o[m], 0, 0, 0);
        }
      }
    }
    __syncthreads();
  }

  // per-wave stats + O^T -> LDS [q=l15][d] bf16 (own region; reused P space)
  if (quad == 0) {
    mbuf[wave][l15] = mr;
    lbuf[wave][l15] = lr;
  }
#pragma unroll
  for (int m = 0; m < 4; ++m) {
    u16x4 pk = {f2b(o[m][0]), f2b(o[m][1]), f2b(o[m][2]), f2b(o[m][3])};
    *(u16x4*)(&Ob[wave][l15 * 72 + 16 * m + quad * 4]) = pk;
  }
  __syncthreads();
  // merge the 2 kv-parity partials per q-row; thread -> row rr, 8-wide chunk
  const int rr = tid >> 3;          // 0..31
  const int cg = (tid & 7) * 8;     // 0..56
  const int qgr = rr >> 4, r16 = rr & 15;
  const float m0 = mbuf[qgr * 2][r16], m1 = mbuf[qgr * 2 + 1][r16];
  const float mstar = fmaxf(m0, m1);
  const float f0 = exp2f(m0 - mstar), f1 = exp2f(m1 - mstar);
  const float lsum = f0 * lbuf[qgr * 2][r16] + f1 * lbuf[qgr * 2 + 1][r16];
  const float inv = 1.0f / lsum;
  s16x8 o0 = *(const s16x8*)(&Ob[qgr * 2][r16 * 72 + cg]);
  s16x8 o1 = *(const s16x8*)(&Ob[qgr * 2 + 1][r16 * 72 + cg]);
  float av[8];
#pragma unroll
  for (int e = 0; e < 8; ++e) {
    float x0 = __builtin_bit_cast(float, ((u32)(u16)o0[e]) << 16);
    float x1 = __builtin_bit_cast(float, ((u32)(u16)o1[e]) << 16);
    av[e] = (f0 * x0 + f1 * x1) * inv;
  }
  float* op = out + ((size_t)b * T_ + qt * 32 + rr) * 64 + cg;
  float4 st0 = {av[0], av[1], av[2], av[3]};
  float4 st1 = {av[4], av[5], av[6], av[7]};
  *(float4*)(op + 0) = st0;
  *(float4*)(op + 4) = st1;
}

extern "C" void kernel_launch(void* const* d_in, const int* in_sizes, int n_in,
                              void* d_out, int out_size, void* d_ws, size_t ws_size,
                              hipStream_t stream) {
  const float* x  = (const float*)d_in[0];
  const float* Wq = (const float*)d_in[1];
  const float* Wk = (const float*)d_in[2];
  const float* Wv = (const float*)d_in[3];
  float* out = (float*)d_out;
  char* ws = (char*)d_ws;
  u16* Wt = (u16*)ws;                                   // 384 KB
  u16* q  = (u16*)(ws + 393216);                        // 2 MB
  u16* k  = (u16*)(ws + 393216 + 2097152);              // 2 MB
  u16* vT = (u16*)(ws + 393216 + 2 * 2097152);          // 2 MB
  hipLaunchKernelGGL(wconv, dim3(48), dim3(256), 0, stream, Wq, Wk, Wv, Wt);
  hipLaunchKernelGGL(proj, dim3(512), dim3(256), 0, stream, x, Wt, q, k, vT);
  hipLaunchKernelGGL(attn, dim3(512), dim3(256), 0, stream, q, k, vT, out);
}